// Round 1
// baseline (169.390 us; speedup 1.0000x reference)
//
#include <hip/hip_runtime.h>
#include <math.h>

#define BHn 16
#define SLEN 4096
#define Dd 64
#define Cc 64
#define NCC 64
#define EPSF 1e-6f

// ---------------------------------------------------------------------------
// Kernel A: per (head, chunk) UT transform.
//   kn = l2norm(k); g = clip(beta); S = kn kn^T (strict lower needed)
//   L = I + strict_lower(g_i * S);  solve L W = g*kn,  L U = g*v  (in LDS)
// ---------------------------------------------------------------------------
__global__ __launch_bounds__(256) void kA(
    const float* __restrict__ kg, const float* __restrict__ vg,
    const float* __restrict__ betag, float* __restrict__ Wg, float* __restrict__ Ug)
{
    const int n = blockIdx.x, bh = blockIdx.y, tid = threadIdx.x;
    __shared__ float kn[64 * 65];   // normalized k rows; becomes W (in-place solve)
    __shared__ float us[64 * 65];   // g*v rows;          becomes U (in-place solve)
    __shared__ float Sm[64 * 64];   // S then g-scaled S
    __shared__ float gl[64];

    const size_t base = ((size_t)bh * SLEN + (size_t)n * Cc) * Dd;
    float4 kv[4], vv[4];
#pragma unroll
    for (int p = 0; p < 4; p++) {
        const int flat = p * 1024 + tid * 4;
        kv[p] = *(const float4*)(kg + base + flat);
        vv[p] = *(const float4*)(vg + base + flat);
    }
    if (tid < 64) {
        float b = betag[(size_t)bh * SLEN + n * Cc + tid];
        gl[tid] = fminf(fmaxf(b, EPSF), 1.0f - EPSF);
    }
    __syncthreads();
    // row norms via 16-lane shuffle groups; write kn and us
#pragma unroll
    for (int p = 0; p < 4; p++) {
        const int row = p * 16 + (tid >> 4);
        const int d0 = (tid & 15) * 4;
        float4 a = kv[p];
        float ss = a.x * a.x + a.y * a.y + a.z * a.z + a.w * a.w;
        ss += __shfl_xor(ss, 1);
        ss += __shfl_xor(ss, 2);
        ss += __shfl_xor(ss, 4);
        ss += __shfl_xor(ss, 8);
        const float inv = 1.0f / (sqrtf(ss) + EPSF);
        float* kr = &kn[row * 65 + d0];
        kr[0] = a.x * inv; kr[1] = a.y * inv; kr[2] = a.z * inv; kr[3] = a.w * inv;
        const float gg = gl[row];
        float4 b = vv[p];
        float* ur = &us[row * 65 + d0];
        ur[0] = b.x * gg; ur[1] = b.y * gg; ur[2] = b.z * gg; ur[3] = b.w * gg;
    }
    __syncthreads();
    // S = kn kn^T, lower-triangular 4x4 tiles only (136 tiles)
    if (tid < 136) {
        int ti = (int)((sqrtf(8.0f * (float)tid + 1.0f) - 1.0f) * 0.5f);
        while (ti * (ti + 1) / 2 > tid) --ti;
        while ((ti + 1) * (ti + 2) / 2 <= tid) ++ti;
        const int tj = tid - ti * (ti + 1) / 2;
        const int i0 = ti * 4, j0 = tj * 4;
        float sa[4][4];
#pragma unroll
        for (int r = 0; r < 4; r++)
#pragma unroll
            for (int c2 = 0; c2 < 4; c2++) sa[r][c2] = 0.f;
#pragma unroll 4
        for (int d = 0; d < 64; d++) {
            float ar[4], bc[4];
#pragma unroll
            for (int r = 0; r < 4; r++) ar[r] = kn[(i0 + r) * 65 + d];
#pragma unroll
            for (int c2 = 0; c2 < 4; c2++) bc[c2] = kn[(j0 + c2) * 65 + d];
#pragma unroll
            for (int r = 0; r < 4; r++)
#pragma unroll
                for (int c2 = 0; c2 < 4; c2++) sa[r][c2] += ar[r] * bc[c2];
        }
#pragma unroll
        for (int r = 0; r < 4; r++)
            *(float4*)&Sm[(i0 + r) * 64 + j0] =
                make_float4(sa[r][0], sa[r][1], sa[r][2], sa[r][3]);
    }
    __syncthreads();
    // scale rows by g[i]:  Sm -> L off-diagonals, kn -> k_beta (solve RHS)
#pragma unroll
    for (int p = 0; p < 16; p++) {
        const int idx = p * 256 + tid;
        const int i = idx >> 6, j = idx & 63;
        const float gg = gl[i];
        Sm[i * 64 + j] *= gg;
        kn[i * 65 + j] *= gg;
    }
    __syncthreads();
    // forward substitution, hierarchical blocks of 8; columns are thread-private
    if (tid < 128) {
        float* P = (tid < 64) ? kn : us;
        const int c = tid & 63;
        float acc[8];
#pragma unroll
        for (int b = 0; b < 8; b++) {
            const int i0 = b * 8;
#pragma unroll
            for (int r = 0; r < 8; r++) acc[r] = P[(i0 + r) * 65 + c];
            for (int j = 0; j < i0; j += 4) {
                const float pj0 = P[(j + 0) * 65 + c];
                const float pj1 = P[(j + 1) * 65 + c];
                const float pj2 = P[(j + 2) * 65 + c];
                const float pj3 = P[(j + 3) * 65 + c];
#pragma unroll
                for (int r = 0; r < 8; r++) {
                    const float4 s4 = *(const float4*)&Sm[(i0 + r) * 64 + j];
                    acc[r] -= s4.x * pj0 + s4.y * pj1 + s4.z * pj2 + s4.w * pj3;
                }
            }
#pragma unroll
            for (int il = 1; il < 8; il++)
#pragma unroll
                for (int jl = 0; jl < 8; jl++)
                    if (jl < il)
                        acc[il] -= Sm[(i0 + il) * 64 + i0 + jl] * acc[jl];
#pragma unroll
            for (int r = 0; r < 8; r++) P[(i0 + r) * 65 + c] = acc[r];
        }
    }
    __syncthreads();
    float* Wdst = Wg + ((size_t)(bh * NCC + n)) * Cc * Dd;
    float* Udst = Ug + ((size_t)(bh * NCC + n)) * Cc * Dd;
#pragma unroll
    for (int p = 0; p < 4; p++) {
        const int flat = p * 1024 + tid * 4;
        const int i = flat >> 6, d0 = flat & 63;
        *(float4*)(Wdst + flat) = make_float4(kn[i * 65 + d0], kn[i * 65 + d0 + 1],
                                              kn[i * 65 + d0 + 2], kn[i * 65 + d0 + 3]);
        *(float4*)(Udst + flat) = make_float4(us[i * 65 + d0], us[i * 65 + d0 + 1],
                                              us[i * 65 + d0 + 2], us[i * 65 + d0 + 3]);
    }
}

// ---------------------------------------------------------------------------
// Kernel B: chunk-level delta rule via the same UT transform.
//   w_m = W[m][63], u_m = U[m][63];  solve (I + strict_lower(w w^T)) Uval = u
// ---------------------------------------------------------------------------
__global__ __launch_bounds__(256) void kB(
    const float* __restrict__ Wg, const float* __restrict__ Ug, float* __restrict__ Uvg)
{
    const int bh = blockIdx.x, tid = threadIdx.x;
    __shared__ float wl[64 * 65];
    __shared__ float uv[64 * 65];
    __shared__ float Sm[64 * 64];
    const int lane = tid & 63, grp = tid >> 6;
#pragma unroll
    for (int i = 0; i < 16; i++) {
        const int m = grp * 16 + i;
        const size_t off = ((size_t)(bh * NCC + m) * Cc + 63) * Dd + lane;
        wl[m * 65 + lane] = Wg[off];
        uv[m * 65 + lane] = Ug[off];
    }
    __syncthreads();
    if (tid < 136) {
        int ti = (int)((sqrtf(8.0f * (float)tid + 1.0f) - 1.0f) * 0.5f);
        while (ti * (ti + 1) / 2 > tid) --ti;
        while ((ti + 1) * (ti + 2) / 2 <= tid) ++ti;
        const int tj = tid - ti * (ti + 1) / 2;
        const int i0 = ti * 4, j0 = tj * 4;
        float sa[4][4];
#pragma unroll
        for (int r = 0; r < 4; r++)
#pragma unroll
            for (int c2 = 0; c2 < 4; c2++) sa[r][c2] = 0.f;
#pragma unroll 4
        for (int d = 0; d < 64; d++) {
            float ar[4], bc[4];
#pragma unroll
            for (int r = 0; r < 4; r++) ar[r] = wl[(i0 + r) * 65 + d];
#pragma unroll
            for (int c2 = 0; c2 < 4; c2++) bc[c2] = wl[(j0 + c2) * 65 + d];
#pragma unroll
            for (int r = 0; r < 4; r++)
#pragma unroll
                for (int c2 = 0; c2 < 4; c2++) sa[r][c2] += ar[r] * bc[c2];
        }
#pragma unroll
        for (int r = 0; r < 4; r++)
            *(float4*)&Sm[(i0 + r) * 64 + j0] =
                make_float4(sa[r][0], sa[r][1], sa[r][2], sa[r][3]);
    }
    __syncthreads();
    if (tid < 64) {
        const int c = tid;
        float acc[8];
#pragma unroll
        for (int b = 0; b < 8; b++) {
            const int i0 = b * 8;
#pragma unroll
            for (int r = 0; r < 8; r++) acc[r] = uv[(i0 + r) * 65 + c];
            for (int j = 0; j < i0; j += 4) {
                const float pj0 = uv[(j + 0) * 65 + c];
                const float pj1 = uv[(j + 1) * 65 + c];
                const float pj2 = uv[(j + 2) * 65 + c];
                const float pj3 = uv[(j + 3) * 65 + c];
#pragma unroll
                for (int r = 0; r < 8; r++) {
                    const float4 s4 = *(const float4*)&Sm[(i0 + r) * 64 + j];
                    acc[r] -= s4.x * pj0 + s4.y * pj1 + s4.z * pj2 + s4.w * pj3;
                }
            }
#pragma unroll
            for (int il = 1; il < 8; il++)
#pragma unroll
                for (int jl = 0; jl < 8; jl++)
                    if (jl < il)
                        acc[il] -= Sm[(i0 + il) * 64 + i0 + jl] * acc[jl];
#pragma unroll
            for (int r = 0; r < 8; r++) uv[(i0 + r) * 65 + c] = acc[r];
        }
    }
    __syncthreads();
    float* dst = Uvg + (size_t)bh * NCC * Dd;
#pragma unroll
    for (int p = 0; p < 4; p++) {
        const int flat = p * 1024 + tid * 4;
        const int i = flat >> 6, d0 = flat & 63;
        *(float4*)(dst + flat) = make_float4(uv[i * 65 + d0], uv[i * 65 + d0 + 1],
                                             uv[i * 65 + d0 + 2], uv[i * 65 + d0 + 3]);
    }
}

// ---------------------------------------------------------------------------
// Kernel C: per (head, chunk) output.
//   h = sum_{m<n} w_m uval_m^T ;  out = qn .* (U - W h) + qn h
// ---------------------------------------------------------------------------
__global__ __launch_bounds__(256) void kC(
    const float* __restrict__ qg, const float* __restrict__ Wg,
    const float* __restrict__ Ug, const float* __restrict__ Uvg,
    float* __restrict__ outg)
{
    const int n = blockIdx.x, bh = blockIdx.y, tid = threadIdx.x;
    __shared__ float bufA[64 * 68];   // phase1: wl[m][d]  phase2: Wt[d][t]
    __shared__ float bufB[64 * 68];   // phase1: uval[m][e] phase2: qt[d][t]
    __shared__ float hb[64 * 68];     // h[d][e]
    const int lane = tid & 63, grp = tid >> 6;
#pragma unroll
    for (int i = 0; i < 16; i++) {
        const int m = grp * 16 + i;
        bufA[m * 68 + lane] = Wg[((size_t)(bh * NCC + m) * Cc + 63) * Dd + lane];
        bufB[m * 68 + lane] = Uvg[(size_t)bh * NCC * Dd + m * Dd + lane];
    }
    __syncthreads();
    const int t0 = (tid >> 4) * 4, e0 = (tid & 15) * 4;   // t0 doubles as d0 for h tile
    float ha[4][4];
#pragma unroll
    for (int r = 0; r < 4; r++)
#pragma unroll
        for (int c2 = 0; c2 < 4; c2++) ha[r][c2] = 0.f;
    for (int m = 0; m < n; m++) {
        const float4 a = *(const float4*)&bufA[m * 68 + t0];
        const float4 b = *(const float4*)&bufB[m * 68 + e0];
        const float av[4] = {a.x, a.y, a.z, a.w};
        const float bv[4] = {b.x, b.y, b.z, b.w};
#pragma unroll
        for (int r = 0; r < 4; r++)
#pragma unroll
            for (int c2 = 0; c2 < 4; c2++) ha[r][c2] += av[r] * bv[c2];
    }
#pragma unroll
    for (int r = 0; r < 4; r++)
        *(float4*)&hb[(t0 + r) * 68 + e0] =
            make_float4(ha[r][0], ha[r][1], ha[r][2], ha[r][3]);
    __syncthreads();
    // phase 2: transpose W_n and normalized q into LDS
    const float* Wn = Wg + ((size_t)(bh * NCC + n)) * Cc * Dd;
#pragma unroll
    for (int i = 0; i < 16; i++) {
        const int t = grp * 16 + i;
        bufA[lane * 68 + t] = Wn[t * Dd + lane];
    }
    const float* qc = qg + ((size_t)bh * SLEN + (size_t)n * Cc) * Dd;
#pragma unroll
    for (int i = 0; i < 16; i++) {
        const int t = grp * 16 + i;
        const float qv = qc[t * Dd + lane];
        float ss = qv * qv;
        ss += __shfl_xor(ss, 1);  ss += __shfl_xor(ss, 2);  ss += __shfl_xor(ss, 4);
        ss += __shfl_xor(ss, 8);  ss += __shfl_xor(ss, 16); ss += __shfl_xor(ss, 32);
        bufB[lane * 68 + t] = qv * (1.0f / (sqrtf(ss) + EPSF));
    }
    __syncthreads();
    float kth[4][4], oin[4][4];
#pragma unroll
    for (int r = 0; r < 4; r++)
#pragma unroll
        for (int c2 = 0; c2 < 4; c2++) { kth[r][c2] = 0.f; oin[r][c2] = 0.f; }
#pragma unroll 4
    for (int d = 0; d < 64; d++) {
        const float4 wv = *(const float4*)&bufA[d * 68 + t0];
        const float4 qv = *(const float4*)&bufB[d * 68 + t0];
        const float4 hv = *(const float4*)&hb[d * 68 + e0];
        const float wa[4] = {wv.x, wv.y, wv.z, wv.w};
        const float qa[4] = {qv.x, qv.y, qv.z, qv.w};
        const float hv4[4] = {hv.x, hv.y, hv.z, hv.w};
#pragma unroll
        for (int r = 0; r < 4; r++)
#pragma unroll
            for (int c2 = 0; c2 < 4; c2++) {
                kth[r][c2] += wa[r] * hv4[c2];
                oin[r][c2] += qa[r] * hv4[c2];
            }
    }
    const float* Un = Ug + ((size_t)(bh * NCC + n)) * Cc * Dd;
    float* oc = outg + ((size_t)bh * SLEN + (size_t)n * Cc) * Dd;
#pragma unroll
    for (int r = 0; r < 4; r++) {
        const int t = t0 + r;
        const float4 u4 = *(const float4*)(Un + t * Dd + e0);
        const float q0 = bufB[(e0 + 0) * 68 + t];
        const float q1 = bufB[(e0 + 1) * 68 + t];
        const float q2 = bufB[(e0 + 2) * 68 + t];
        const float q3 = bufB[(e0 + 3) * 68 + t];
        float4 o;
        o.x = q0 * (u4.x - kth[r][0]) + oin[r][0];
        o.y = q1 * (u4.y - kth[r][1]) + oin[r][1];
        o.z = q2 * (u4.z - kth[r][2]) + oin[r][2];
        o.w = q3 * (u4.w - kth[r][3]) + oin[r][3];
        *(float4*)(oc + t * Dd + e0) = o;
    }
}

extern "C" void kernel_launch(void* const* d_in, const int* in_sizes, int n_in,
                              void* d_out, int out_size, void* d_ws, size_t ws_size,
                              hipStream_t stream) {
    const float* q    = (const float*)d_in[0];
    const float* k    = (const float*)d_in[1];
    const float* v    = (const float*)d_in[2];
    const float* beta = (const float*)d_in[3];
    float* out = (float*)d_out;

    float* Wg  = (float*)d_ws;                       // [BH][NC][64][64]
    float* Ug  = Wg + (size_t)BHn * NCC * Cc * Dd;   // [BH][NC][64][64]
    float* Uvg = Ug + (size_t)BHn * NCC * Cc * Dd;   // [BH][NC][64]

    kA<<<dim3(NCC, BHn), 256, 0, stream>>>(k, v, beta, Wg, Ug);
    kB<<<dim3(BHn), 256, 0, stream>>>(Wg, Ug, Uvg);
    kC<<<dim3(NCC, BHn), 256, 0, stream>>>(q, Wg, Ug, Uvg, out);
}

// Round 2
// 166.362 us; speedup vs baseline: 1.0182x; 1.0182x over previous
//
#include <hip/hip_runtime.h>
#include <math.h>

#define BHn 16
#define SLEN 4096
#define Dd 64
#define Cc 64
#define NCC 64
#define EPSF 1e-6f
#define P68 68

// ---------------------------------------------------------------------------
// kA: per (head, chunk) UT transform, fully transposed layouts.
//   KT[d][t] = l2norm(k)[t][d];  PW[d][t] = g_t * KT[d][t];  PU[e][t] = g_t*v[t][e]
//   SM[i][j] = g_i * (kn_i . kn_j)  (strict lower used)
//   solve rows-in-thread: PW,PU become W^T, U^T. Write WT,UT + last rows.
// ---------------------------------------------------------------------------
__global__ __launch_bounds__(256) void kA(
    const float* __restrict__ kg, const float* __restrict__ vg,
    const float* __restrict__ betag, float* __restrict__ WTg, float* __restrict__ UTg,
    float* __restrict__ wlast, float* __restrict__ ulast)
{
    const int n = blockIdx.x, bh = blockIdx.y, tid = threadIdx.x;
    __shared__ float KT[64 * P68];   // kn^T ; later reused as PU -> U^T
    __shared__ float PW[64 * P68];   // k_beta^T -> W^T
    __shared__ float SM[64 * 64];
    __shared__ float gl[64];
    __shared__ float rno[64];

    const size_t base = ((size_t)bh * SLEN + (size_t)n * Cc) * Dd;

    // phase 1: per-token k row norms (coalesced float4 + 16-lane shuffle), beta clip
#pragma unroll
    for (int p = 0; p < 4; p++) {
        const int flat = p * 1024 + tid * 4;
        const int row = flat >> 6;
        const float4 a = *(const float4*)(kg + base + flat);
        float ss = a.x * a.x + a.y * a.y + a.z * a.z + a.w * a.w;
        ss += __shfl_xor(ss, 1); ss += __shfl_xor(ss, 2);
        ss += __shfl_xor(ss, 4); ss += __shfl_xor(ss, 8);
        if ((tid & 15) == 0) rno[row] = 1.0f / (sqrtf(ss) + EPSF);
    }
    if (tid < 64) {
        const float b = betag[(size_t)bh * SLEN + n * Cc + tid];
        gl[tid] = fminf(fmaxf(b, EPSF), 1.0f - EPSF);
    }
    __syncthreads();

    // phase 2: build KT and PW via transposed (per-instr coalesced) global reads
    {
        const int c = tid & 63, w = tid >> 6;   // c = dim, wave w handles tokens 16w..16w+15
        float buf[16];
#pragma unroll
        for (int j = 0; j < 16; j++)
            buf[j] = kg[base + (size_t)(w * 16 + j) * 64 + c];
        float* ktr = &KT[c * P68];
        float* pwr = &PW[c * P68];
#pragma unroll
        for (int s = 0; s < 4; s++) {
            const int i0 = w * 16 + s * 4;
            float4 kt4, pw4;
            kt4.x = buf[s*4+0] * rno[i0+0]; kt4.y = buf[s*4+1] * rno[i0+1];
            kt4.z = buf[s*4+2] * rno[i0+2]; kt4.w = buf[s*4+3] * rno[i0+3];
            pw4.x = kt4.x * gl[i0+0]; pw4.y = kt4.y * gl[i0+1];
            pw4.z = kt4.z * gl[i0+2]; pw4.w = kt4.w * gl[i0+3];
            *(float4*)&ktr[i0] = kt4;
            *(float4*)&pwr[i0] = pw4;
        }
    }
    __syncthreads();

    // phase 3: SM lower 4x4 tiles from KT (broadcast b128 reads), row-scaled by g
    if (tid < 136) {
        int ti = (int)((sqrtf(8.0f * (float)tid + 1.0f) - 1.0f) * 0.5f);
        while (ti * (ti + 1) / 2 > tid) --ti;
        while ((ti + 1) * (ti + 2) / 2 <= tid) ++ti;
        const int tj = tid - ti * (ti + 1) / 2;
        const int i0 = ti * 4, j0 = tj * 4;
        float sa[4][4];
#pragma unroll
        for (int r = 0; r < 4; r++)
#pragma unroll
            for (int c2 = 0; c2 < 4; c2++) sa[r][c2] = 0.f;
        for (int d = 0; d < 64; d++) {
            const float4 a = *(const float4*)&KT[d * P68 + i0];
            const float4 b = *(const float4*)&KT[d * P68 + j0];
            const float av[4] = {a.x, a.y, a.z, a.w};
            const float bv[4] = {b.x, b.y, b.z, b.w};
#pragma unroll
            for (int r = 0; r < 4; r++)
#pragma unroll
                for (int c2 = 0; c2 < 4; c2++) sa[r][c2] += av[r] * bv[c2];
        }
#pragma unroll
        for (int r = 0; r < 4; r++) {
            const float gg = gl[i0 + r];
            *(float4*)&SM[(i0 + r) * 64 + j0] =
                make_float4(sa[r][0] * gg, sa[r][1] * gg, sa[r][2] * gg, sa[r][3] * gg);
        }
    }
    __syncthreads();

    // phase 4: build PU (over KT space) via transposed global reads of v, scaled by g
    {
        const int c = tid & 63, w = tid >> 6;
        float buf[16];
#pragma unroll
        for (int j = 0; j < 16; j++)
            buf[j] = vg[base + (size_t)(w * 16 + j) * 64 + c];
        float* pur = &KT[c * P68];
#pragma unroll
        for (int s = 0; s < 4; s++) {
            const int i0 = w * 16 + s * 4;
            float4 pu4;
            pu4.x = buf[s*4+0] * gl[i0+0]; pu4.y = buf[s*4+1] * gl[i0+1];
            pu4.z = buf[s*4+2] * gl[i0+2]; pu4.w = buf[s*4+3] * gl[i0+3];
            *(float4*)&pur[i0] = pu4;
        }
    }
    __syncthreads();

    // phase 5: dual-column forward substitution, one wave, rows in own LDS row
    if (tid < 64) {
        const int c = tid;
        float* pw = &PW[c * P68];
        float* pu = &KT[c * P68];
        for (int b = 0; b < 8; b++) {
            const int i0 = b * 8;
            float aw[8], au[8];
            {
                float4 w0 = *(const float4*)&pw[i0], w1 = *(const float4*)&pw[i0 + 4];
                float4 u0 = *(const float4*)&pu[i0], u1 = *(const float4*)&pu[i0 + 4];
                aw[0]=w0.x; aw[1]=w0.y; aw[2]=w0.z; aw[3]=w0.w;
                aw[4]=w1.x; aw[5]=w1.y; aw[6]=w1.z; aw[7]=w1.w;
                au[0]=u0.x; au[1]=u0.y; au[2]=u0.z; au[3]=u0.w;
                au[4]=u1.x; au[5]=u1.y; au[6]=u1.z; au[7]=u1.w;
            }
            for (int j = 0; j < i0; j += 4) {
                const float4 w4 = *(const float4*)&pw[j];
                const float4 u4 = *(const float4*)&pu[j];
#pragma unroll
                for (int r = 0; r < 8; r++) {
                    const float4 s4 = *(const float4*)&SM[(i0 + r) * 64 + j];
                    aw[r] -= s4.x * w4.x + s4.y * w4.y + s4.z * w4.z + s4.w * w4.w;
                    au[r] -= s4.x * u4.x + s4.y * u4.y + s4.z * u4.z + s4.w * u4.w;
                }
            }
#pragma unroll
            for (int il = 1; il < 8; il++)
#pragma unroll
                for (int jl = 0; jl < 8; jl++)
                    if (jl < il) {
                        const float s = SM[(i0 + il) * 64 + i0 + jl];
                        aw[il] -= s * aw[jl];
                        au[il] -= s * au[jl];
                    }
            *(float4*)&pw[i0]     = make_float4(aw[0], aw[1], aw[2], aw[3]);
            *(float4*)&pw[i0 + 4] = make_float4(aw[4], aw[5], aw[6], aw[7]);
            *(float4*)&pu[i0]     = make_float4(au[0], au[1], au[2], au[3]);
            *(float4*)&pu[i0 + 4] = make_float4(au[4], au[5], au[6], au[7]);
        }
        // last rows (this thread wrote them; no barrier needed)
        wlast[((size_t)bh * NCC + n) * 64 + c] = pw[63];
        ulast[((size_t)bh * NCC + n) * 64 + c] = pu[63];
    }
    __syncthreads();

    // phase 6: write W^T, U^T (coalesced b128)
    {
        float* wdst = WTg + (size_t)(bh * NCC + n) * Cc * Dd;
        float* udst = UTg + (size_t)(bh * NCC + n) * Cc * Dd;
#pragma unroll
        for (int p = 0; p < 4; p++) {
            const int flat = p * 1024 + tid * 4;
            const int c = flat >> 6, pos = flat & 63;
            *(float4*)(wdst + flat) = *(const float4*)&PW[c * P68 + pos];
            *(float4*)(udst + flat) = *(const float4*)&KT[c * P68 + pos];
        }
    }
}

// ---------------------------------------------------------------------------
// kB: chunk-level delta rule. S'[i][j] = w_i . w_j ; solve (I+sl(S')) Uval = u
//   Inputs dense wlast/ulast, output Uval row-major [m][e].
// ---------------------------------------------------------------------------
__global__ __launch_bounds__(256) void kB(
    const float* __restrict__ wlast, const float* __restrict__ ulast,
    float* __restrict__ Uvg)
{
    const int bh = blockIdx.x, tid = threadIdx.x;
    __shared__ float WLT[64 * P68];  // w^T [d][m]
    __shared__ float PV[64 * P68];   // u^T [e][m] -> Uval^T
    __shared__ float SM[64 * 64];
    const size_t gbase = (size_t)bh * NCC * 64;

    {
        const int c = tid & 63, w = tid >> 6;
        float bw[16], bu[16];
#pragma unroll
        for (int j = 0; j < 16; j++) {
            bw[j] = wlast[gbase + (size_t)(w * 16 + j) * 64 + c];
            bu[j] = ulast[gbase + (size_t)(w * 16 + j) * 64 + c];
        }
#pragma unroll
        for (int s = 0; s < 4; s++) {
            const int i0 = w * 16 + s * 4;
            *(float4*)&WLT[c * P68 + i0] = make_float4(bw[s*4], bw[s*4+1], bw[s*4+2], bw[s*4+3]);
            *(float4*)&PV[c * P68 + i0]  = make_float4(bu[s*4], bu[s*4+1], bu[s*4+2], bu[s*4+3]);
        }
    }
    __syncthreads();

    if (tid < 136) {
        int ti = (int)((sqrtf(8.0f * (float)tid + 1.0f) - 1.0f) * 0.5f);
        while (ti * (ti + 1) / 2 > tid) --ti;
        while ((ti + 1) * (ti + 2) / 2 <= tid) ++ti;
        const int tj = tid - ti * (ti + 1) / 2;
        const int i0 = ti * 4, j0 = tj * 4;
        float sa[4][4];
#pragma unroll
        for (int r = 0; r < 4; r++)
#pragma unroll
            for (int c2 = 0; c2 < 4; c2++) sa[r][c2] = 0.f;
        for (int d = 0; d < 64; d++) {
            const float4 a = *(const float4*)&WLT[d * P68 + i0];
            const float4 b = *(const float4*)&WLT[d * P68 + j0];
            const float av[4] = {a.x, a.y, a.z, a.w};
            const float bv[4] = {b.x, b.y, b.z, b.w};
#pragma unroll
            for (int r = 0; r < 4; r++)
#pragma unroll
                for (int c2 = 0; c2 < 4; c2++) sa[r][c2] += av[r] * bv[c2];
        }
#pragma unroll
        for (int r = 0; r < 4; r++)
            *(float4*)&SM[(i0 + r) * 64 + j0] =
                make_float4(sa[r][0], sa[r][1], sa[r][2], sa[r][3]);
    }
    __syncthreads();

    if (tid < 64) {
        float* pv = &PV[tid * P68];
        for (int b = 0; b < 8; b++) {
            const int i0 = b * 8;
            float au[8];
            {
                float4 u0 = *(const float4*)&pv[i0], u1 = *(const float4*)&pv[i0 + 4];
                au[0]=u0.x; au[1]=u0.y; au[2]=u0.z; au[3]=u0.w;
                au[4]=u1.x; au[5]=u1.y; au[6]=u1.z; au[7]=u1.w;
            }
            for (int j = 0; j < i0; j += 4) {
                const float4 u4 = *(const float4*)&pv[j];
#pragma unroll
                for (int r = 0; r < 8; r++) {
                    const float4 s4 = *(const float4*)&SM[(i0 + r) * 64 + j];
                    au[r] -= s4.x * u4.x + s4.y * u4.y + s4.z * u4.z + s4.w * u4.w;
                }
            }
#pragma unroll
            for (int il = 1; il < 8; il++)
#pragma unroll
                for (int jl = 0; jl < 8; jl++)
                    if (jl < il)
                        au[il] -= SM[(i0 + il) * 64 + i0 + jl] * au[jl];
            *(float4*)&pv[i0]     = make_float4(au[0], au[1], au[2], au[3]);
            *(float4*)&pv[i0 + 4] = make_float4(au[4], au[5], au[6], au[7]);
        }
    }
    __syncthreads();

    // write Uval row-major [m][e]
    {
        const int m = tid & 63, w = tid >> 6;
#pragma unroll
        for (int s = 0; s < 4; s++) {
            const int e = w * 16 + s * 4;
            float4 f;
            f.x = PV[(e + 0) * P68 + m]; f.y = PV[(e + 1) * P68 + m];
            f.z = PV[(e + 2) * P68 + m]; f.w = PV[(e + 3) * P68 + m];
            *(float4*)(Uvg + gbase + (size_t)m * 64 + e) = f;
        }
    }
}

// ---------------------------------------------------------------------------
// kC: per (head, chunk) output.
//   h[d][e] = sum_{m<n} wlast[m][d]*Uval[m][e]
//   out = qn .* (U - W h) + qn h   (U^T read from global, W^T staged, q^T built)
// ---------------------------------------------------------------------------
__global__ __launch_bounds__(256) void kC(
    const float* __restrict__ qg, const float* __restrict__ WTg,
    const float* __restrict__ UTg, const float* __restrict__ wlast,
    const float* __restrict__ Uvg, float* __restrict__ outg)
{
    const int n = blockIdx.x, bh = blockIdx.y, tid = threadIdx.x;
    __shared__ float X1[64 * P68];   // ph1: A[m][d]=wlast ; ph3: Wt[d][t]
    __shared__ float X2[64 * P68];   // ph1: B[m][e]=Uval  ; ph3: qt[d][t]
    __shared__ float HB[64 * 64];    // h[d][e]
    __shared__ float rnq[64];

    const size_t qbase = ((size_t)bh * SLEN + (size_t)n * Cc) * Dd;
    const size_t lbase = (size_t)bh * NCC * 64;

    // ph1 loads + q norm pass (independent)
#pragma unroll
    for (int p = 0; p < 4; p++) {
        const int flat = p * 1024 + tid * 4;
        const int m = flat >> 6, d = flat & 63;
        *(float4*)&X1[m * P68 + d] = *(const float4*)(wlast + lbase + flat);
        *(float4*)&X2[m * P68 + d] = *(const float4*)(Uvg + lbase + flat);
        const float4 a = *(const float4*)(qg + qbase + flat);
        float ss = a.x * a.x + a.y * a.y + a.z * a.z + a.w * a.w;
        ss += __shfl_xor(ss, 1); ss += __shfl_xor(ss, 2);
        ss += __shfl_xor(ss, 4); ss += __shfl_xor(ss, 8);
        if ((tid & 15) == 0) rnq[m] = 1.0f / (sqrtf(ss) + EPSF);
    }
    __syncthreads();

    const int t0 = (tid >> 4) * 4, e0 = (tid & 15) * 4;
    float ha[4][4];
#pragma unroll
    for (int r = 0; r < 4; r++)
#pragma unroll
        for (int c2 = 0; c2 < 4; c2++) ha[r][c2] = 0.f;
    for (int m = 0; m < n; m++) {
        const float4 a = *(const float4*)&X1[m * P68 + t0];
        const float4 b = *(const float4*)&X2[m * P68 + e0];
        const float av[4] = {a.x, a.y, a.z, a.w};
        const float bv[4] = {b.x, b.y, b.z, b.w};
#pragma unroll
        for (int r = 0; r < 4; r++)
#pragma unroll
            for (int c2 = 0; c2 < 4; c2++) ha[r][c2] += av[r] * bv[c2];
    }
#pragma unroll
    for (int r = 0; r < 4; r++)
        *(float4*)&HB[(t0 + r) * 64 + e0] =
            make_float4(ha[r][0], ha[r][1], ha[r][2], ha[r][3]);
    __syncthreads();

    // ph2: Wt into X1 (flat, no transpose); qt into X2 (transposed global reads)
    {
        const float* wsrc = WTg + (size_t)(bh * NCC + n) * Cc * Dd;
#pragma unroll
        for (int p = 0; p < 4; p++) {
            const int flat = p * 1024 + tid * 4;
            const int d = flat >> 6, t = flat & 63;
            *(float4*)&X1[d * P68 + t] = *(const float4*)(wsrc + flat);
        }
    }
    __syncthreads();
    {
        const int c = tid & 63, w = tid >> 6;
        float buf[16];
#pragma unroll
        for (int j = 0; j < 16; j++)
            buf[j] = qg[qbase + (size_t)(w * 16 + j) * 64 + c];
        float* qtr = &X2[c * P68];
#pragma unroll
        for (int s = 0; s < 4; s++) {
            const int i0 = w * 16 + s * 4;
            float4 q4;
            q4.x = buf[s*4+0] * rnq[i0+0]; q4.y = buf[s*4+1] * rnq[i0+1];
            q4.z = buf[s*4+2] * rnq[i0+2]; q4.w = buf[s*4+3] * rnq[i0+3];
            *(float4*)&qtr[i0] = q4;
        }
    }
    __syncthreads();

    // ph3: kth = W h, oin = qn h
    float kth[4][4], oin[4][4];
#pragma unroll
    for (int r = 0; r < 4; r++)
#pragma unroll
        for (int c2 = 0; c2 < 4; c2++) { kth[r][c2] = 0.f; oin[r][c2] = 0.f; }
    for (int d = 0; d < 64; d++) {
        const float4 wv = *(const float4*)&X1[d * P68 + t0];
        const float4 qv = *(const float4*)&X2[d * P68 + t0];
        const float4 hv = *(const float4*)&HB[d * 64 + e0];
        const float wa[4] = {wv.x, wv.y, wv.z, wv.w};
        const float qa[4] = {qv.x, qv.y, qv.z, qv.w};
        const float hv4[4] = {hv.x, hv.y, hv.z, hv.w};
#pragma unroll
        for (int r = 0; r < 4; r++)
#pragma unroll
            for (int c2 = 0; c2 < 4; c2++) {
                kth[r][c2] += wa[r] * hv4[c2];
                oin[r][c2] += qa[r] * hv4[c2];
            }
    }

    // epilogue: uval from U^T (global), qn from qt; out row-major
    const float* usrc = UTg + (size_t)(bh * NCC + n) * Cc * Dd;
    float uu[4][4], qq[4][4];
#pragma unroll
    for (int s = 0; s < 4; s++) {
        const float4 u4 = *(const float4*)(usrc + (e0 + s) * 64 + t0);
        const float4 q4 = *(const float4*)&X2[(e0 + s) * P68 + t0];
        uu[s][0] = u4.x; uu[s][1] = u4.y; uu[s][2] = u4.z; uu[s][3] = u4.w;
        qq[s][0] = q4.x; qq[s][1] = q4.y; qq[s][2] = q4.z; qq[s][3] = q4.w;
    }
    float* oc = outg + qbase;
#pragma unroll
    for (int r = 0; r < 4; r++) {
        float4 o;
        o.x = qq[0][r] * (uu[0][r] - kth[r][0]) + oin[r][0];
        o.y = qq[1][r] * (uu[1][r] - kth[r][1]) + oin[r][1];
        o.z = qq[2][r] * (uu[2][r] - kth[r][2]) + oin[r][2];
        o.w = qq[3][r] * (uu[3][r] - kth[r][3]) + oin[r][3];
        *(float4*)(oc + (size_t)(t0 + r) * 64 + e0) = o;
    }
}

extern "C" void kernel_launch(void* const* d_in, const int* in_sizes, int n_in,
                              void* d_out, int out_size, void* d_ws, size_t ws_size,
                              hipStream_t stream) {
    const float* q    = (const float*)d_in[0];
    const float* k    = (const float*)d_in[1];
    const float* v    = (const float*)d_in[2];
    const float* beta = (const float*)d_in[3];
    float* out = (float*)d_out;

    float* WTg   = (float*)d_ws;                              // [BH][NC][64][64] (W^T)
    float* UTg   = WTg + (size_t)BHn * NCC * Cc * Dd;         // [BH][NC][64][64] (U^T)
    float* wlast = UTg + (size_t)BHn * NCC * Cc * Dd;         // [BH][NC][64]
    float* ulast = wlast + (size_t)BHn * NCC * 64;            // [BH][NC][64]
    float* Uvg   = ulast + (size_t)BHn * NCC * 64;            // [BH][NC][64]

    kA<<<dim3(NCC, BHn), 256, 0, stream>>>(k, v, beta, WTg, UTg, wlast, ulast);
    kB<<<dim3(BHn), 256, 0, stream>>>(wlast, ulast, Uvg);
    kC<<<dim3(NCC, BHn), 256, 0, stream>>>(q, WTg, UTg, wlast, Uvg, out);
}